// Round 11
// baseline (97.849 us; speedup 1.0000x reference)
//
#include <hip/hip_runtime.h>
#include <math.h>

#define NI 256
#define NJ 256
#define NK 1024
#define JCHUNK 32
#define WPB 4
#define KSEG 256
#define NQ 70              // quads per CT row: 3 pad + 64 own + 3 pad
#define PADQ 3

typedef float float4v __attribute__((ext_vector_type(4)));

__device__ __forceinline__ float finalize(float n, float d) {
    // semblance <= 1 (Cauchy-Schwarz): no overflow. 0/0 -> 0*inf = nan -> 1.0.
    float r = n * __builtin_amdgcn_rcpf(d);
    if (!(r == r)) r = 1.0f;
    return r;
}

// 20-window sums from the transposed per-quad cumsum table.
// B = CT + p, CT row-major [4][NQ]; C[q][i] = CT[i][q]; Q[q] = CT[3][q].
// Window for output e: global k in [kb-10+e, kb+9+e], kb = own quad start.
__device__ __forceinline__ void kwin_ct(const float* __restrict__ B, float Qown,
                                        float& w0, float& w1, float& w2, float& w3) {
    const float A1 = B[1 * NQ - 3];   // C[p-3][1]
    const float A2 = B[2 * NQ - 3];   // C[p-3][2]
    const float A3 = B[3 * NQ - 3];   // Q[p-3]
    const float F0 = B[0 * NQ - 2];   // C[p-2][0]
    const float F3 = B[3 * NQ - 2];   // Q[p-2]
    const float G3 = B[3 * NQ - 1];   // Q[p-1]
    const float H3 = B[3 * NQ + 1];   // Q[p+1]
    const float I1 = B[1 * NQ + 2];   // C[p+2][1]
    const float I2 = B[2 * NQ + 2];   // C[p+2][2]
    const float I3 = B[3 * NQ + 2];   // Q[p+2]
    const float J0 = B[0 * NQ + 3];   // C[p+3][0]
    const float Qs = (F3 + G3) + (Qown + H3);   // quads p-2..p+1 full
    w0 = (A3 - A1) + Qs + I1;         // p-3 elems 2,3 | 16 | p+2 elems 0,1
    w1 = (A3 - A2) + Qs + I2;         // p-3 elem 3   | 16 | p+2 elems 0..2
    w2 = Qs + I3;                     //               16 + p+2 full
    w3 = (Qs - F0) + (I3 + J0);       // p-2 elems 1..3 | 12 | p+2 full | p+3 elem 0
}

__global__ __launch_bounds__(256)
void semblance_kernel(const float* __restrict__ x, float* __restrict__ out) {
    // wave-private transposed cumsum tables; zero s_barriers in the kernel
    __shared__ float ctn[WPB][4][NQ];
    __shared__ float ctd[WPB][4][NQ];

    const int tid  = threadIdx.x;
    const int lane = tid & 63;
    const int wave = tid >> 6;
    const int i    = blockIdx.y;
    const int j0   = blockIdx.x * JCHUNK;
    const int k0s  = wave * KSEG;
    const int kb   = k0s + 4 * lane;       // this lane's first global k
    const int p    = lane + PADQ;          // own quad column in CT

    float* Cn = &ctn[wave][0][0];
    float* Cd = &ctd[wave][0][0];

    // halo duty: lanes 0-2 -> left quads 0,1,2 ; lanes 3-5 -> right 67,68,69
    const bool hal = (lane < 6);
    const int  hq  = (lane < 3) ? lane : (64 + lane);
    const int  hk  = k0s + (hq - PADQ) * 4;    // global k of halo quad start
    const bool hok = hal && (hk >= 0) && (hk < NK);

    // zero halo columns once (invalid ones stay zero forever)
    if (hal) {
        Cn[0*NQ + hq] = 0.f; Cn[1*NQ + hq] = 0.f; Cn[2*NQ + hq] = 0.f; Cn[3*NQ + hq] = 0.f;
        Cd[0*NQ + hq] = 0.f; Cd[1*NQ + hq] = 0.f; Cd[2*NQ + hq] = 0.f; Cd[3*NQ + hq] = 0.f;
    }

    const float* xi = x + (size_t)i * NJ * NK;
    const float* xk = xi + kb;
    const float* xh = xi + hk;              // only dereferenced when hok

    // main running sums + register ring over rows j0-2..j0+2
    float4v r0, r1, r2, r3, r4;
    r0 = (j0 - 2 >= 0) ? *(const float4v*)(xk + (size_t)(j0 - 2) * NK) : (float4v)0.f;
    r1 = (j0 - 1 >= 0) ? *(const float4v*)(xk + (size_t)(j0 - 1) * NK) : (float4v)0.f;
    r2 = *(const float4v*)(xk + (size_t)j0 * NK);
    r3 = (j0 + 1 < NJ) ? *(const float4v*)(xk + (size_t)(j0 + 1) * NK) : (float4v)0.f;
    r4 = (j0 + 2 < NJ) ? *(const float4v*)(xk + (size_t)(j0 + 2) * NK) : (float4v)0.f;
    float4v s = (r0 + r1) + (r2 + r3) + r4;
    float4v t = (r0 * r0 + r1 * r1) + (r2 * r2 + r3 * r3) + r4 * r4;

    // halo running sums (ring-less: outgoing row reloaded, L1-hot)
    float4v hs = (float4v)0.f, ht = (float4v)0.f;
    if (hok) {
        #pragma unroll
        for (int dj = -2; dj <= 2; ++dj) {
            const int r = j0 + dj;
            if (r >= 0 && r < NJ) {
                float4v v = *(const float4v*)(xh + (size_t)r * NK);
                hs += v; ht += v * v;
            }
        }
    }

    #pragma unroll 2
    for (int jj = 0; jj < JCHUNK; ++jj) {
        const int j = j0 + jj;

        // own quad values for row j
        const float4v un = s * s;

        // within-quad cumsums -> transposed LDS columns (stride-1 across lanes)
        const float cn0 = un[0], cn1 = cn0 + un[1], cn2 = cn1 + un[2], cn3 = cn2 + un[3];
        const float cd0 = t[0],  cd1 = cd0 + t[1],  cd2 = cd1 + t[2],  cd3 = cd2 + t[3];
        Cn[0*NQ + p] = cn0; Cn[1*NQ + p] = cn1; Cn[2*NQ + p] = cn2; Cn[3*NQ + p] = cn3;
        Cd[0*NQ + p] = cd0; Cd[1*NQ + p] = cd1; Cd[2*NQ + p] = cd2; Cd[3*NQ + p] = cd3;

        if (hok) {
            const float4v hu = hs * hs;
            const float h0 = hu[0], h1 = h0 + hu[1], h2 = h1 + hu[2], h3 = h2 + hu[3];
            Cn[0*NQ + hq] = h0; Cn[1*NQ + hq] = h1; Cn[2*NQ + hq] = h2; Cn[3*NQ + hq] = h3;
            const float g0 = ht[0], g1 = g0 + ht[1], g2 = g1 + ht[2], g3 = g2 + ht[3];
            Cd[0*NQ + hq] = g0; Cd[1*NQ + hq] = g1; Cd[2*NQ + hq] = g2; Cd[3*NQ + hq] = g3;
        }

        // issue next-row loads now; consumed only at iteration end
        float4v n = (float4v)0.f, hn = (float4v)0.f, hm = (float4v)0.f;
        if (j + 3 < NJ) n = *(const float4v*)(xk + (size_t)(j + 3) * NK);
        if (hok) {
            if (j + 3 < NJ) hn = *(const float4v*)(xh + (size_t)(j + 3) * NK);
            if (j - 2 >= 0) hm = *(const float4v*)(xh + (size_t)(j - 2) * NK);
        }

        // wave-internal write->read ordering (DS pipe in-order per wave)
        __builtin_amdgcn_wave_barrier();
        asm volatile("" ::: "memory");

        float wn0, wn1, wn2, wn3, wd0, wd1, wd2, wd3;
        kwin_ct(Cn + p, cn3, wn0, wn1, wn2, wn3);
        kwin_ct(Cd + p, cd3, wd0, wd1, wd2, wd3);

        const int jlo = (j - 2 < 0) ? 0 : j - 2;
        const int jhi = (j + 2 > NJ - 1) ? NJ - 1 : j + 2;
        const float norm = (float)(jhi - jlo + 1);

        float4v o;
        o[0] = finalize(wn0, wd0 * norm);
        o[1] = finalize(wn1, wd1 * norm);
        o[2] = finalize(wn2, wd2 * norm);
        o[3] = finalize(wn3, wd3 * norm);
        __builtin_nontemporal_store(o, (float4v*)(out + ((size_t)i * NJ + j) * NK + kb));

        // slide running sums from the ring (no j-2 reload on the main path)
        s += n - r0;
        t += n * n - r0 * r0;
        r0 = r1; r1 = r2; r2 = r3; r3 = r4; r4 = n;
        if (hok) { hs += hn - hm; ht += hn * hn - hm * hm; }

        // order this iteration's LDS reads before next iteration's writes
        __builtin_amdgcn_wave_barrier();
        asm volatile("" ::: "memory");
    }
}

extern "C" void kernel_launch(void* const* d_in, const int* in_sizes, int n_in,
                              void* d_out, int out_size, void* d_ws, size_t ws_size,
                              hipStream_t stream) {
    const float* x = (const float*)d_in[0];
    float* out = (float*)d_out;
    dim3 grid(NJ / JCHUNK, NI);   // (8, 256) = 2048 blocks, 4 independent waves each
    semblance_kernel<<<grid, 256, 0, stream>>>(x, out);
}

// Round 12
// 95.187 us; speedup vs baseline: 1.0280x; 1.0280x over previous
//
#include <hip/hip_runtime.h>
#include <math.h>

#define NI 256
#define NJ 256
#define NK 1024
#define JCHUNK 32
#define WPB 4
#define KSEG 256
#define WREG 288   // 16 left halo/pad + 256 own + 16 right halo (floats)

typedef float float4v __attribute__((ext_vector_type(4)));

__device__ __forceinline__ float finalize(float n, float d) {
    // semblance <= 1 (Cauchy-Schwarz): no overflow. 0/0 -> 0*inf = nan -> 1.0.
    float r = n * __builtin_amdgcn_rcpf(d);
    if (!(r == r)) r = 1.0f;
    return r;
}

// 20-wide sliding k-window, all-aligned b128 reads (conflict-free).
// p0 points at float idx (own_base - 12) of the logical row.
__device__ __forceinline__ void kwindow(const float* __restrict__ p0,
                                        float& w0, float& w1, float& w2, float& w3) {
    const float4v* p = (const float4v*)p0;
    float4v q0 = p[0], q1 = p[1], q2 = p[2], q3 = p[3], q4 = p[4], q5 = p[5], q6 = p[6];
    float4v midv = (q1 + q2) + (q3 + q4);
    float mid = (midv[0] + midv[1]) + (midv[2] + midv[3]);
    w0 = q0[2] + q0[3] + mid + q5[0] + q5[1];
    w1 = w0 + q5[2] - q0[2];
    w2 = w1 + q5[3] - q0[3];
    w3 = w2 + q6[0] - q1[0];
}

__global__ __launch_bounds__(256)
void semblance_kernel(const float* __restrict__ x, float* __restrict__ out) {
    // wave-private regions: [wave][row A/B][num|den][WREG]; zero s_barriers
    __shared__ __align__(16) float lds[WPB][2][2][WREG];

    const int tid  = threadIdx.x;
    const int lane = tid & 63;
    const int wave = tid >> 6;
    const int i    = blockIdx.y;
    const int j0   = blockIdx.x * JCHUNK;
    const int k0s  = wave * KSEG;
    const int kb   = k0s + 4 * lane;

    float* PnA = &lds[wave][0][0][0];
    float* PdA = &lds[wave][0][1][0];
    float* PnB = &lds[wave][1][0][0];
    float* PdB = &lds[wave][1][1][0];

    // halo duty: lanes 0-2 -> left quads (idx 4,8,12), lanes 3-5 -> right (272,276,280)
    const bool hal = (lane < 6);
    const int  hidx = (lane < 3) ? (4 + 4 * lane) : (272 + 4 * (lane - 3));
    const int  hk   = k0s + hidx - 16;
    const bool hok  = hal && (hk >= 0) && (hk < NK);

    if (hal) {   // zero halo quads once; invalid columns stay zero forever
        *(float4v*)(PnA + hidx) = (float4v)0.f;
        *(float4v*)(PdA + hidx) = (float4v)0.f;
        *(float4v*)(PnB + hidx) = (float4v)0.f;
        *(float4v*)(PdB + hidx) = (float4v)0.f;
    }

    const float* xi = x + (size_t)i * NJ * NK;
    const float* xk = xi + kb;
    const float* xh = xi + hk;              // only dereferenced when hok

    // ---- init: rows j0-2 .. j0+3 ----
    // ring r0..r4 = x[j0-1 .. j0+3]; m2 = x[j0-2] (transient)
    float4v m2, r0, r1, r2, r3, r4;
    m2 = (j0 - 2 >= 0) ? *(const float4v*)(xk + (size_t)(j0 - 2) * NK) : (float4v)0.f;
    r0 = (j0 - 1 >= 0) ? *(const float4v*)(xk + (size_t)(j0 - 1) * NK) : (float4v)0.f;
    r1 = *(const float4v*)(xk + (size_t)(j0 + 0) * NK);
    r2 = *(const float4v*)(xk + (size_t)(j0 + 1) * NK);
    r3 = *(const float4v*)(xk + (size_t)(j0 + 2) * NK);
    r4 = *(const float4v*)(xk + (size_t)(j0 + 3) * NK);
    float4v sA = (m2 + r0) + (r1 + r2) + r3;                       // s(j0)
    float4v tA = (m2 * m2 + r0 * r0) + (r1 * r1 + r2 * r2) + r3 * r3;
    float4v sB = sA + r4 - m2;                                      // s(j0+1)
    float4v tB = tA + r4 * r4 - m2 * m2;

    // halo running sums for rows j0 and j0+1
    float4v hsA = (float4v)0.f, htA = (float4v)0.f, hsB = (float4v)0.f, htB = (float4v)0.f;
    if (hok) {
        float4v hm2 = (j0 - 2 >= 0) ? *(const float4v*)(xh + (size_t)(j0 - 2) * NK) : (float4v)0.f;
        float4v h0  = (j0 - 1 >= 0) ? *(const float4v*)(xh + (size_t)(j0 - 1) * NK) : (float4v)0.f;
        float4v h1  = *(const float4v*)(xh + (size_t)(j0 + 0) * NK);
        float4v h2  = *(const float4v*)(xh + (size_t)(j0 + 1) * NK);
        float4v h3  = *(const float4v*)(xh + (size_t)(j0 + 2) * NK);
        float4v h4  = *(const float4v*)(xh + (size_t)(j0 + 3) * NK);
        hsA = (hm2 + h0) + (h1 + h2) + h3;
        htA = (hm2 * hm2 + h0 * h0) + (h1 * h1 + h2 * h2) + h3 * h3;
        hsB = hsA + h4 - hm2;
        htB = htA + h4 * h4 - hm2 * hm2;
    }

    #pragma unroll 1
    for (int it = 0; it < JCHUNK / 2; ++it) {
        const int jA = j0 + 2 * it;
        const int jB = jA + 1;

        // publish both rows (own quads + halo quads)
        *(float4v*)(PnA + 16 + 4 * lane) = sA * sA;
        *(float4v*)(PdA + 16 + 4 * lane) = tA;
        *(float4v*)(PnB + 16 + 4 * lane) = sB * sB;
        *(float4v*)(PdB + 16 + 4 * lane) = tB;
        if (hok) {
            *(float4v*)(PnA + hidx) = hsA * hsA;
            *(float4v*)(PdA + hidx) = htA;
            *(float4v*)(PnB + hidx) = hsB * hsB;
            *(float4v*)(PdB + hidx) = htB;
        }

        // prefetch slide rows; consumed only at iteration END
        float4v nA = (float4v)0.f, nB = (float4v)0.f;
        if (jA + 4 < NJ) nA = *(const float4v*)(xk + (size_t)(jA + 4) * NK);
        if (jA + 5 < NJ) nB = *(const float4v*)(xk + (size_t)(jA + 5) * NK);
        float4v hnA = (float4v)0.f, hnB = (float4v)0.f, hmA = (float4v)0.f, hmB = (float4v)0.f;
        if (hok) {
            if (jA + 4 < NJ) hnA = *(const float4v*)(xh + (size_t)(jA + 4) * NK);
            if (jA + 5 < NJ) hnB = *(const float4v*)(xh + (size_t)(jA + 5) * NK);
            if (jA - 1 >= 0) hmA = *(const float4v*)(xh + (size_t)(jA - 1) * NK);
            hmB = *(const float4v*)(xh + (size_t)jA * NK);
        }

        // wave-internal write->read ordering (DS pipe in-order per wave)
        __builtin_amdgcn_wave_barrier();
        asm volatile("" ::: "memory");

        // two independent window chains in flight
        float an0, an1, an2, an3, ad0, ad1, ad2, ad3;
        float bn0, bn1, bn2, bn3, bd0, bd1, bd2, bd3;
        kwindow(PnA + 4 + 4 * lane, an0, an1, an2, an3);
        kwindow(PdA + 4 + 4 * lane, ad0, ad1, ad2, ad3);
        kwindow(PnB + 4 + 4 * lane, bn0, bn1, bn2, bn3);
        kwindow(PdB + 4 + 4 * lane, bd0, bd1, bd2, bd3);

        const int jloA = (jA - 2 < 0) ? 0 : jA - 2;
        const int jhiA = (jA + 2 > NJ - 1) ? NJ - 1 : jA + 2;
        const float normA = (float)(jhiA - jloA + 1);
        const int jloB = (jB - 2 < 0) ? 0 : jB - 2;
        const int jhiB = (jB + 2 > NJ - 1) ? NJ - 1 : jB + 2;
        const float normB = (float)(jhiB - jloB + 1);

        float4v oA, oB;
        oA[0] = finalize(an0, ad0 * normA);
        oA[1] = finalize(an1, ad1 * normA);
        oA[2] = finalize(an2, ad2 * normA);
        oA[3] = finalize(an3, ad3 * normA);
        oB[0] = finalize(bn0, bd0 * normB);
        oB[1] = finalize(bn1, bd1 * normB);
        oB[2] = finalize(bn2, bd2 * normB);
        oB[3] = finalize(bn3, bd3 * normB);
        __builtin_nontemporal_store(oA, (float4v*)(out + ((size_t)i * NJ + jA) * NK + kb));
        __builtin_nontemporal_store(oB, (float4v*)(out + ((size_t)i * NJ + jB) * NK + kb));

        // slide both rows forward by 2 (loads land here, far from issue)
        float4v sA2 = sB + nA - r0;
        float4v tA2 = tB + nA * nA - r0 * r0;
        sB = sA2 + nB - r1;
        tB = tA2 + nB * nB - r1 * r1;
        sA = sA2; tA = tA2;
        r0 = r2; r1 = r3; r2 = r4; r3 = nA; r4 = nB;
        if (hok) {
            float4v hsA2 = hsB + hnA - hmA;
            float4v htA2 = htB + hnA * hnA - hmA * hmA;
            hsB = hsA2 + hnB - hmB;
            htB = htA2 + hnB * hnB - hmB * hmB;
            hsA = hsA2; htA = htA2;
        }

        // order this iteration's LDS reads before next iteration's writes
        __builtin_amdgcn_wave_barrier();
        asm volatile("" ::: "memory");
    }
}

extern "C" void kernel_launch(void* const* d_in, const int* in_sizes, int n_in,
                              void* d_out, int out_size, void* d_ws, size_t ws_size,
                              hipStream_t stream) {
    const float* x = (const float*)d_in[0];
    float* out = (float*)d_out;
    dim3 grid(NJ / JCHUNK, NI);   // (8, 256) = 2048 blocks, 4 independent waves each
    semblance_kernel<<<grid, 256, 0, stream>>>(x, out);
}